// Round 7
// baseline (138.269 us; speedup 1.0000x reference)
//
#include <hip/hip_runtime.h>
#include <hip/hip_bf16.h>
#include <math.h>

typedef __bf16 bf16;
typedef __bf16 bf16x8 __attribute__((ext_vector_type(8)));
typedef __bf16 bf16x2 __attribute__((ext_vector_type(2)));
typedef float f32x4 __attribute__((ext_vector_type(4)));
typedef float f32x16 __attribute__((ext_vector_type(16)));

#define D_MODEL 1024
#define SEQ 1024
#define BATCH 4
#define NHEAD 16
#define MTOT (BATCH*SEQ)   // 4096

// scores computed in exp2-space: fold 1/sqrt(64) * log2(e) into Q projection
#define QSCALE 0.18033688011112042f
#define MASKNEG -1e9f

// ---------------- fused f32 -> bf16 casts (7 tensors, one launch) ----------------
__global__ void cast_all(const float* __restrict__ s0, const float* __restrict__ s1,
                         const float* __restrict__ s2, const float* __restrict__ s3,
                         const float* __restrict__ s4, const float* __restrict__ s5,
                         const float* __restrict__ s6,
                         bf16* d0, bf16* d1, bf16* d2, bf16* d3, bf16* d4, bf16* d5, bf16* d6) {
    int z = blockIdx.y;
    const float* s; bf16* d; int n;
    switch (z) {
        case 0: s = s0; d = d0; n = MTOT * D_MODEL; break;
        case 1: s = s1; d = d1; n = MTOT * D_MODEL; break;
        case 2: s = s2; d = d2; n = MTOT * D_MODEL; break;
        case 3: s = s3; d = d3; n = D_MODEL * D_MODEL; break;
        case 4: s = s4; d = d4; n = D_MODEL * D_MODEL; break;
        case 5: s = s5; d = d5; n = D_MODEL * D_MODEL; break;
        default: s = s6; d = d6; n = D_MODEL * D_MODEL; break;
    }
    int idx = (blockIdx.x * blockDim.x + threadIdx.x) * 8;
    int stride = gridDim.x * blockDim.x * 8;
    for (int i = idx; i < n; i += stride) {
        const float4* p = (const float4*)(s + i);
        float4 a = p[0], b = p[1];
        bf16x8 o;
        o[0] = (bf16)a.x; o[1] = (bf16)a.y; o[2] = (bf16)a.z; o[3] = (bf16)a.w;
        o[4] = (bf16)b.x; o[5] = (bf16)b.y; o[6] = (bf16)b.z; o[7] = (bf16)b.w;
        *(bf16x8*)(d + i) = o;
    }
}

// ---------------- GEMM: C[M,N] = A[M,K] @ W[N,K]^T + bias ----------------
// Double-buffered LDS, ONE barrier per K-step: stage(next) -> MFMA(cur) -> barrier.
template<typename OT, int MODE>
__global__ __launch_bounds__(256, 3)
void gemm_bt(const bf16* __restrict__ A0, const bf16* __restrict__ A1, const bf16* __restrict__ A2,
             const bf16* __restrict__ W0, const bf16* __restrict__ W1, const bf16* __restrict__ W2,
             const float* __restrict__ bias0, const float* __restrict__ bias1, const float* __restrict__ bias2,
             OT* __restrict__ O0, OT* __restrict__ O1, OT* __restrict__ O2) {
    constexpr int BK = 32;
    constexpr int K = D_MODEL;
    constexpr int NT = K / BK;   // 32
    __shared__ alignas(16) bf16 As[2][128 * BK];
    __shared__ alignas(16) bf16 Bs[2][128 * BK];

    int z = (MODE == 0) ? blockIdx.z : 0;
    const bf16* A = (z == 0) ? A0 : (z == 1) ? A1 : A2;
    const bf16* W = (z == 0) ? W0 : (z == 1) ? W1 : W2;
    const float* bias = (z == 0) ? bias0 : (z == 1) ? bias1 : bias2;
    OT* Out = (z == 0) ? O0 : (z == 1) ? O1 : O2;

    int tid = threadIdx.x;
    int lane = tid & 63, w = tid >> 6;
    int l15 = lane & 15, l4 = lane >> 4;
    int m0 = blockIdx.x * 128;
    int n0 = blockIdx.y * 128;
    int wm = w >> 1, wn = w & 1;

    f32x4 acc[4][4] = {};

    int srow = lane >> 2;
    int scol = (lane & 3) * 8;

    auto stage = [&](int buf, int kt) {
#pragma unroll
        for (int i = 0; i < 2; ++i) {
            int seg = w * 2 + i;
            int row = seg * 16 + srow;
            const bf16* srcA = A + (size_t)(m0 + row) * K + kt * BK + scol;
            const bf16* srcB = W + (size_t)(n0 + row) * K + kt * BK + scol;
            __builtin_amdgcn_global_load_lds(
                (const __attribute__((address_space(1))) void*)srcA,
                (__attribute__((address_space(3))) void*)(&As[buf][seg * 512]), 16, 0, 0);
            __builtin_amdgcn_global_load_lds(
                (const __attribute__((address_space(1))) void*)srcB,
                (__attribute__((address_space(3))) void*)(&Bs[buf][seg * 512]), 16, 0, 0);
        }
    };

    stage(0, 0);
    __syncthreads();

    for (int kt = 0; kt < NT; ++kt) {
        int cur = kt & 1;
        if (kt + 1 < NT) stage(cur ^ 1, kt + 1);

        const bf16* pa = &As[cur][(wm * 64 + l15) * BK + l4 * 8];
        const bf16* pb = &Bs[cur][(wn * 64 + l15) * BK + l4 * 8];
        bf16x8 af[4], bv[4];
#pragma unroll
        for (int m = 0; m < 4; ++m) af[m] = *(const bf16x8*)(pa + m * 16 * BK);
#pragma unroll
        for (int n = 0; n < 4; ++n) bv[n] = *(const bf16x8*)(pb + n * 16 * BK);
#pragma unroll
        for (int m = 0; m < 4; ++m)
#pragma unroll
            for (int n = 0; n < 4; ++n)
                acc[m][n] = __builtin_amdgcn_mfma_f32_16x16x32_bf16(af[m], bv[n], acc[m][n], 0, 0, 0);

        __syncthreads();
    }

    float bload[4];
#pragma unroll
    for (int n = 0; n < 4; ++n) bload[n] = bias[n0 + wn * 64 + n * 16 + l15];

    if (MODE == 0 && z == 2) {
        // V stored transposed: VT[(b*1024 + h*64+d)][s]
#pragma unroll
        for (int m = 0; m < 4; ++m) {
            int row = m0 + wm * 64 + m * 16 + l4 * 4;
#pragma unroll
            for (int n = 0; n < 4; ++n) {
                int col = n0 + wn * 64 + n * 16 + l15;
                float bl = bload[n];
#pragma unroll
                for (int r = 0; r < 4; ++r) {
                    float vv = acc[m][n][r] + bl;
                    int rr = row + r;
                    int bb = rr >> 10, s = rr & 1023;
                    Out[((size_t)(bb * 1024 + col)) * 1024 + s] = (OT)vv;
                }
            }
        }
    } else {
        const float sc = (MODE == 0 && z == 0) ? QSCALE : 1.0f;
#pragma unroll
        for (int m = 0; m < 4; ++m) {
            int row = m0 + wm * 64 + m * 16 + l4 * 4;
#pragma unroll
            for (int n = 0; n < 4; ++n) {
                int col = n0 + wn * 64 + n * 16 + l15;
                float bl = bload[n];
#pragma unroll
                for (int r = 0; r < 4; ++r) {
                    float vv = (acc[m][n][r] + bl) * sc;
                    Out[(size_t)(row + r) * D_MODEL + col] = (OT)vv;
                }
            }
        }
    }
}

// ---------------- Flash attention fwd: BARRIER-FREE wave-independent version ----------------
// 4 waves x 32 q; each wave streams its K/V tiles DIRECTLY from global into MFMA
// register fragments (no LDS, no __syncthreads in the loop). K double-buffered in regs
// (prefetch next tile during current compute); V issued before QK^T, consumed after
// softmax (~400cy later). D=64: A-frag of K = row kv, 16B d-slice; B-frag of V (from VT
// [d][s] layout) = row d, 16B kv-slice. Adjacent ks slices share 64B lines -> L1-friendly;
// per-head K/V L2-resident on its XCD (swizzle).
__device__ __forceinline__ unsigned pkbf(float lo, float hi2) {
    bf16x2 t; t[0] = (bf16)lo; t[1] = (bf16)hi2;
    return __builtin_bit_cast(unsigned, t);
}

__global__ __launch_bounds__(256, 2)
void attn_fwd(const bf16* __restrict__ Qp, const bf16* __restrict__ Kp,
              const bf16* __restrict__ VT, const int* __restrict__ maskp,
              bf16* __restrict__ ctx) {
    __shared__ alignas(16) float madd2[SEQ];   // 4 KB
    __shared__ int tflag[16];

    int tid = threadIdx.x;
    int lane = tid & 63, w = tid >> 6;      // 4 waves
    int l31 = lane & 31, hi = lane >> 5;

    // XCD swizzle: 512 blocks = 8 XCDs x 64; 8 whole heads per XCD.
    int fid = blockIdx.x;
    int xcd = fid & 7, idx = fid >> 3;       // idx 0..63
    int by = xcd * 8 + (idx >> 3);           // head-batch 0..63
    int bx = idx & 7;                        // q-block 0..7
    int b = by >> 4, h = by & 15;
    int q0 = bx * 128;

    // ---- mask precompute: madd2[1024] + per-64-tile flags (one barrier, then none) ----
    {
#pragma unroll
        for (int i = 0; i < 4; ++i) {
            int pos = tid + i * 256;
            madd2[pos] = maskp[b * SEQ + pos] ? 0.f : MASKNEG;
        }
#pragma unroll
        for (int i = 0; i < 4; ++i) {
            int t = w * 4 + i;
            unsigned long long bl = __ballot(maskp[b * SEQ + t * 64 + lane] != 0);
            if (lane == 0) tflag[t] = (bl == ~0ull);
        }
    }
    __syncthreads();

    // Q B-fragments (col=q=lane&31, k-slot ks: d = ks*16 + hi*8 + j)
    bf16x8 qf[4];
    {
        const bf16* qb = Qp + ((size_t)(b * SEQ + q0 + w * 32 + l31)) * D_MODEL + h * 64 + hi * 8;
#pragma unroll
        for (int ks = 0; ks < 4; ++ks) qf[ks] = *(const bf16x8*)(qb + ks * 16);
    }

    // K A-frag base: row kv -> lane l31(+32), k-elems = d = ks*16 + hi*8 + j
    const bf16* kb_ = Kp + ((size_t)(b * SEQ)) * D_MODEL + h * 64 + hi * 8;
    // V B-frag base: col d = l31(+32), k-elems = kv = ks*16 + hi*8 + j (VT rows = d)
    const bf16* vb_ = VT + ((size_t)(b * 1024 + h * 64 + l31)) * SEQ + hi * 8;

    auto loadK = [&](bf16x8* dst, int kv0) {
        const bf16* p0 = kb_ + (size_t)(kv0 + l31) * D_MODEL;
        const bf16* p1 = kb_ + (size_t)(kv0 + 32 + l31) * D_MODEL;
#pragma unroll
        for (int ks = 0; ks < 4; ++ks) {
            dst[ks]     = *(const bf16x8*)(p0 + ks * 16);
            dst[4 + ks] = *(const bf16x8*)(p1 + ks * 16);
        }
    };
    auto loadV = [&](bf16x8* dst, int kv0) {
#pragma unroll
        for (int ks = 0; ks < 4; ++ks) {
            dst[ks]     = *(const bf16x8*)(vb_ + kv0 + ks * 16);
            dst[4 + ks] = *(const bf16x8*)(vb_ + (size_t)32 * SEQ + kv0 + ks * 16);
        }
    };

    f32x16 oacc0 = {}, oacc1 = {};
    float lsum = 0.f;

    bf16x8 kfA[8], kfB[8], vf[8];
    loadK(kfA, 0);

    // one 64-kv tile with K-frags kf (already loaded), prefetching next K into kn
    auto tile = [&](const bf16x8* kf, bf16x8* kn, int kt) {
        int kv0 = kt * 64;
        if (kt + 1 < 16) loadK(kn, kv0 + 64);   // prefetch next K (consumed next iter)
        loadV(vf, kv0);                          // V for this tile (consumed after softmax)

        // ---- QK^T (swapped): S^T[kv][q] ----
        f32x16 p0 = {}, p1 = {};
        __builtin_amdgcn_s_setprio(1);
#pragma unroll
        for (int ks = 0; ks < 4; ++ks) {
            p0 = __builtin_amdgcn_mfma_f32_32x32x16_bf16(kf[ks],     qf[ks], p0, 0, 0, 0);
            p1 = __builtin_amdgcn_mfma_f32_32x32x16_bf16(kf[4 + ks], qf[ks], p1, 0, 0, 0);
        }
        __builtin_amdgcn_s_setprio(0);

        // ---- exp2 + row-sum (reg r -> kv = kv0 + (r&3) + 8*(r>>2) + 4*hi) ----
        float a0 = 0.f, a1 = 0.f, a2 = 0.f, a3 = 0.f;
        const float* mb = &madd2[kv0];
        if (tflag[kt]) {
#pragma unroll
            for (int g = 0; g < 4; ++g) {
                float s0 = 0.f, s1 = 0.f;
#pragma unroll
                for (int c = 0; c < 4; ++c) {
                    int r = g * 4 + c;
                    float e0 = exp2f(p0[r]);
                    float e1 = exp2f(p1[r]);
                    p0[r] = e0; p1[r] = e1;
                    s0 += e0; s1 += e1;
                }
                if (g == 0) a0 = s0 + s1;
                else if (g == 1) a1 = s0 + s1;
                else if (g == 2) a2 = s0 + s1;
                else a3 = s0 + s1;
            }
        } else {
#pragma unroll
            for (int g = 0; g < 4; ++g) {
                f32x4 mk0 = *(const f32x4*)(mb + g * 8 + hi * 4);
                f32x4 mk1 = *(const f32x4*)(mb + 32 + g * 8 + hi * 4);
                float s0 = 0.f, s1 = 0.f;
#pragma unroll
                for (int c = 0; c < 4; ++c) {
                    int r = g * 4 + c;
                    float e0 = exp2f(p0[r] + mk0[c]);
                    float e1 = exp2f(p1[r] + mk1[c]);
                    p0[r] = e0; p1[r] = e1;
                    s0 += e0; s1 += e1;
                }
                if (g == 0) a0 = s0 + s1;
                else if (g == 1) a1 = s0 + s1;
                else if (g == 2) a2 = s0 + s1;
                else a3 = s0 + s1;
            }
        }
        float acc_s = (a0 + a1) + (a2 + a3);
        acc_s += __shfl_xor(acc_s, 32);
        lsum += acc_s;

        // ---- pack P -> PV A-fragments (cvt_pk + permlane32_swap) ----
        union FragU { bf16x8 v; unsigned u[4]; };
        FragU pa0, pa1, pa2, pa3;
#define PKSW(PV, RA, RB, DST)  { \
            unsigned a_ = pkbf(PV[RA], PV[(RA) + 1]); \
            unsigned b_ = pkbf(PV[RB], PV[(RB) + 1]); \
            auto rr_ = __builtin_amdgcn_permlane32_swap(a_, b_, false, false); \
            DST.u[((RA) & 3) >> 1] = rr_[0]; DST.u[(((RA) & 3) >> 1) + 2] = rr_[1]; }
        PKSW(p0, 0, 4,  pa0);
        PKSW(p0, 2, 6,  pa0);
        PKSW(p0, 8, 12, pa1);
        PKSW(p0, 10, 14, pa1);
        PKSW(p1, 0, 4,  pa2);
        PKSW(p1, 2, 6,  pa2);
        PKSW(p1, 8, 12, pa3);
        PKSW(p1, 10, 14, pa3);
#undef PKSW

        // ---- PV: O += P[q][kv] . V[kv][d] ----
        __builtin_amdgcn_s_setprio(1);
#pragma unroll
        for (int i = 0; i < 4; ++i) {
            bf16x8 pav = (i == 0) ? pa0.v : (i == 1) ? pa1.v : (i == 2) ? pa2.v : pa3.v;
            oacc0 = __builtin_amdgcn_mfma_f32_32x32x16_bf16(pav, vf[i],     oacc0, 0, 0, 0);
            oacc1 = __builtin_amdgcn_mfma_f32_32x32x16_bf16(pav, vf[4 + i], oacc1, 0, 0, 0);
        }
        __builtin_amdgcn_s_setprio(0);
    };

    // 16 tiles, ping-pong K buffers with static indexing (rule #20)
#pragma unroll 1
    for (int kt2 = 0; kt2 < 8; ++kt2) {
        tile(kfA, kfB, 2 * kt2);
        tile(kfB, kfA, 2 * kt2 + 1);
    }

    // ---- epilogue: normalize and store ----
#pragma unroll
    for (int g = 0; g < 4; ++g) {
#pragma unroll
        for (int c = 0; c < 4; ++c) {
            int r = g * 4 + c;
            int qloc = c + g * 8 + hi * 4;
            float sden = __shfl(lsum, qloc);
            float inv = 1.0f / sden;
            int qg = q0 + w * 32 + qloc;
            size_t base = ((size_t)(b * SEQ + qg)) * D_MODEL + h * 64;
            ctx[base + l31]      = (bf16)(oacc0[r] * inv);
            ctx[base + 32 + l31] = (bf16)(oacc1[r] * inv);
        }
    }
}

// ---------------- launch ----------------
extern "C" void kernel_launch(void* const* d_in, const int* in_sizes, int n_in,
                              void* d_out, int out_size, void* d_ws, size_t ws_size,
                              hipStream_t stream) {
    const float* q  = (const float*)d_in[0];
    const float* k  = (const float*)d_in[1];
    const float* v  = (const float*)d_in[2];
    const int* mask = (const int*)d_in[3];
    const float* Wq = (const float*)d_in[4];
    const float* bq = (const float*)d_in[5];
    const float* Wk = (const float*)d_in[6];
    const float* bk = (const float*)d_in[7];
    const float* Wv = (const float*)d_in[8];
    const float* bv = (const float*)d_in[9];
    const float* Wo = (const float*)d_in[10];
    const float* bo = (const float*)d_in[11];
    float* out = (float*)d_out;

    char* ws = (char*)d_ws;
    size_t szQKV = (size_t)MTOT * D_MODEL * sizeof(bf16);   // 8 MB
    size_t szW = (size_t)D_MODEL * D_MODEL * sizeof(bf16);  // 2 MB
    bf16* qb  = (bf16*)ws; ws += szQKV;
    bf16* kb  = (bf16*)ws; ws += szQKV;
    bf16* vb  = (bf16*)ws; ws += szQKV;
    bf16* Wqb = (bf16*)ws; ws += szW;
    bf16* Wkb = (bf16*)ws; ws += szW;
    bf16* Wvb = (bf16*)ws; ws += szW;
    bf16* Wob = (bf16*)ws; ws += szW;
    bf16* Qp  = (bf16*)ws; ws += szQKV;
    bf16* Kp  = (bf16*)ws; ws += szQKV;
    bf16* VT  = (bf16*)ws; ws += szQKV;   // transposed V: [B][H][64][SEQ]
    bf16* ctx = (bf16*)ws; ws += szQKV;

    dim3 gc(512, 7, 1);
    cast_all<<<gc, 256, 0, stream>>>(q, k, v, Wq, Wk, Wv, Wo,
                                     qb, kb, vb, Wqb, Wkb, Wvb, Wob);

    dim3 g1(MTOT / 128, D_MODEL / 128, 3);
    gemm_bt<bf16, 0><<<g1, 256, 0, stream>>>(qb, kb, vb, Wqb, Wkb, Wvb,
                                             bq, bk, bv, Qp, Kp, VT);

    attn_fwd<<<dim3(512), 256, 0, stream>>>(Qp, Kp, VT, mask, ctx);

    dim3 g3(MTOT / 128, D_MODEL / 128, 1);
    gemm_bt<float, 1><<<g3, 256, 0, stream>>>(ctx, ctx, ctx, Wob, Wob, Wob,
                                              bo, bo, bo, out, out, out);
}

// Round 8
// 111.882 us; speedup vs baseline: 1.2358x; 1.2358x over previous
//
#include <hip/hip_runtime.h>
#include <hip/hip_bf16.h>
#include <math.h>

typedef __bf16 bf16;
typedef __bf16 bf16x8 __attribute__((ext_vector_type(8)));
typedef __bf16 bf16x2 __attribute__((ext_vector_type(2)));
typedef float f32x4 __attribute__((ext_vector_type(4)));
typedef float f32x16 __attribute__((ext_vector_type(16)));

#define D_MODEL 1024
#define SEQ 1024
#define BATCH 4
#define NHEAD 16
#define MTOT (BATCH*SEQ)   // 4096

// scores computed in exp2-space: fold 1/sqrt(64) * log2(e) into Q projection
#define QSCALE 0.18033688011112042f
#define MASKNEG -1e9f
#define EXP2(x) __builtin_amdgcn_exp2f(x)

// ---------------- fused f32 -> bf16 casts (7 tensors, one launch) ----------------
__global__ void cast_all(const float* __restrict__ s0, const float* __restrict__ s1,
                         const float* __restrict__ s2, const float* __restrict__ s3,
                         const float* __restrict__ s4, const float* __restrict__ s5,
                         const float* __restrict__ s6,
                         bf16* d0, bf16* d1, bf16* d2, bf16* d3, bf16* d4, bf16* d5, bf16* d6) {
    int z = blockIdx.y;
    const float* s; bf16* d; int n;
    switch (z) {
        case 0: s = s0; d = d0; n = MTOT * D_MODEL; break;
        case 1: s = s1; d = d1; n = MTOT * D_MODEL; break;
        case 2: s = s2; d = d2; n = MTOT * D_MODEL; break;
        case 3: s = s3; d = d3; n = D_MODEL * D_MODEL; break;
        case 4: s = s4; d = d4; n = D_MODEL * D_MODEL; break;
        case 5: s = s5; d = d5; n = D_MODEL * D_MODEL; break;
        default: s = s6; d = d6; n = D_MODEL * D_MODEL; break;
    }
    int idx = (blockIdx.x * blockDim.x + threadIdx.x) * 8;
    int stride = gridDim.x * blockDim.x * 8;
    for (int i = idx; i < n; i += stride) {
        const float4* p = (const float4*)(s + i);
        float4 a = p[0], b = p[1];
        bf16x8 o;
        o[0] = (bf16)a.x; o[1] = (bf16)a.y; o[2] = (bf16)a.z; o[3] = (bf16)a.w;
        o[4] = (bf16)b.x; o[5] = (bf16)b.y; o[6] = (bf16)b.z; o[7] = (bf16)b.w;
        *(bf16x8*)(d + i) = o;
    }
}

// ---------------- GEMM: C[M,N] = A[M,K] @ W[N,K]^T + bias ----------------
// Double-buffered LDS, ONE barrier per K-step: stage(next) -> MFMA(cur) -> barrier.
template<typename OT, int MODE>
__global__ __launch_bounds__(256, 3)
void gemm_bt(const bf16* __restrict__ A0, const bf16* __restrict__ A1, const bf16* __restrict__ A2,
             const bf16* __restrict__ W0, const bf16* __restrict__ W1, const bf16* __restrict__ W2,
             const float* __restrict__ bias0, const float* __restrict__ bias1, const float* __restrict__ bias2,
             OT* __restrict__ O0, OT* __restrict__ O1, OT* __restrict__ O2) {
    constexpr int BK = 32;
    constexpr int K = D_MODEL;
    constexpr int NT = K / BK;   // 32
    __shared__ alignas(16) bf16 As[2][128 * BK];
    __shared__ alignas(16) bf16 Bs[2][128 * BK];

    int z = (MODE == 0) ? blockIdx.z : 0;
    const bf16* A = (z == 0) ? A0 : (z == 1) ? A1 : A2;
    const bf16* W = (z == 0) ? W0 : (z == 1) ? W1 : W2;
    const float* bias = (z == 0) ? bias0 : (z == 1) ? bias1 : bias2;
    OT* Out = (z == 0) ? O0 : (z == 1) ? O1 : O2;

    int tid = threadIdx.x;
    int lane = tid & 63, w = tid >> 6;
    int l15 = lane & 15, l4 = lane >> 4;
    int m0 = blockIdx.x * 128;
    int n0 = blockIdx.y * 128;
    int wm = w >> 1, wn = w & 1;

    f32x4 acc[4][4] = {};

    int srow = lane >> 2;
    int scol = (lane & 3) * 8;

    auto stage = [&](int buf, int kt) {
#pragma unroll
        for (int i = 0; i < 2; ++i) {
            int seg = w * 2 + i;
            int row = seg * 16 + srow;
            const bf16* srcA = A + (size_t)(m0 + row) * K + kt * BK + scol;
            const bf16* srcB = W + (size_t)(n0 + row) * K + kt * BK + scol;
            __builtin_amdgcn_global_load_lds(
                (const __attribute__((address_space(1))) void*)srcA,
                (__attribute__((address_space(3))) void*)(&As[buf][seg * 512]), 16, 0, 0);
            __builtin_amdgcn_global_load_lds(
                (const __attribute__((address_space(1))) void*)srcB,
                (__attribute__((address_space(3))) void*)(&Bs[buf][seg * 512]), 16, 0, 0);
        }
    };

    stage(0, 0);
    __syncthreads();

    for (int kt = 0; kt < NT; ++kt) {
        int cur = kt & 1;
        if (kt + 1 < NT) stage(cur ^ 1, kt + 1);

        const bf16* pa = &As[cur][(wm * 64 + l15) * BK + l4 * 8];
        const bf16* pb = &Bs[cur][(wn * 64 + l15) * BK + l4 * 8];
        bf16x8 af[4], bv[4];
#pragma unroll
        for (int m = 0; m < 4; ++m) af[m] = *(const bf16x8*)(pa + m * 16 * BK);
#pragma unroll
        for (int n = 0; n < 4; ++n) bv[n] = *(const bf16x8*)(pb + n * 16 * BK);
#pragma unroll
        for (int m = 0; m < 4; ++m)
#pragma unroll
            for (int n = 0; n < 4; ++n)
                acc[m][n] = __builtin_amdgcn_mfma_f32_16x16x32_bf16(af[m], bv[n], acc[m][n], 0, 0, 0);

        __syncthreads();
    }

    float bload[4];
#pragma unroll
    for (int n = 0; n < 4; ++n) bload[n] = bias[n0 + wn * 64 + n * 16 + l15];

    if (MODE == 0 && z == 2) {
        // V stored transposed: VT[(b*1024 + h*64+d)][s]
#pragma unroll
        for (int m = 0; m < 4; ++m) {
            int row = m0 + wm * 64 + m * 16 + l4 * 4;
#pragma unroll
            for (int n = 0; n < 4; ++n) {
                int col = n0 + wn * 64 + n * 16 + l15;
                float bl = bload[n];
#pragma unroll
                for (int r = 0; r < 4; ++r) {
                    float vv = acc[m][n][r] + bl;
                    int rr = row + r;
                    int bb = rr >> 10, s = rr & 1023;
                    Out[((size_t)(bb * 1024 + col)) * 1024 + s] = (OT)vv;
                }
            }
        }
    } else {
        const float sc = (MODE == 0 && z == 0) ? QSCALE : 1.0f;
#pragma unroll
        for (int m = 0; m < 4; ++m) {
            int row = m0 + wm * 64 + m * 16 + l4 * 4;
#pragma unroll
            for (int n = 0; n < 4; ++n) {
                int col = n0 + wn * 64 + n * 16 + l15;
                float bl = bload[n];
#pragma unroll
                for (int r = 0; r < 4; ++r) {
                    float vv = (acc[m][n][r] + bl) * sc;
                    Out[(size_t)(row + r) * D_MODEL + col] = (OT)vv;
                }
            }
        }
    }
}

// ---------------- Flash attention fwd: intra-block split-KV, 8 waves ----------------
// Waves 0-3: kv [0,512); waves 4-7: kv [512,1024); same 128 q-rows (wave pair (wl, wl+4)
// shares q-sub wl). No-max exp2-space softmax => partials merge by PURE ADDITION in an
// LDS epilogue (no extra kernel/global traffic). 16 waves/CU (2 blocks x 8 waves).
// K LDS [kv][64] and VT LDS [d][kv-slice], XOR-swizzled (chunk8 ^= row&7) via
// pre-swizzled global source + linear global_load_lds. Raw v_exp_f32 for exp2.
__device__ __forceinline__ unsigned pkbf(float lo, float hi2) {
    bf16x2 t; t[0] = (bf16)lo; t[1] = (bf16)hi2;
    return __builtin_bit_cast(unsigned, t);
}

__global__ __launch_bounds__(512, 4)
void attn_fwd(const bf16* __restrict__ Qp, const bf16* __restrict__ Kp,
              const bf16* __restrict__ VT, const int* __restrict__ maskp,
              bf16* __restrict__ ctx) {
    // smem layout: [0,32K) Kbuf [2buf][2half][4096]; [32K,64K) Vbuf same;
    // [64K,68K) madd2[1024] f32; [68K,+64) tflag[16].
    // After main loop (post-barrier): [0,32K) reused as Omrg[4][32][64] f32,
    // [32K,+512) as Lmrg[4][32] f32.
    __shared__ alignas(16) unsigned char smem[69760];
    bf16* Kbuf = (bf16*)smem;
    bf16* Vbuf = (bf16*)(smem + 32768);
    float* madd2 = (float*)(smem + 65536);
    int* tflag = (int*)(smem + 69632);

    int tid = threadIdx.x;
    int lane = tid & 63, w = tid >> 6;      // 8 waves
    int l31 = lane & 31, hi = lane >> 5;
    int hh = w >> 2, wl = w & 3;            // kv-half, wave-in-half (= q-sub)

    // XCD swizzle: 512 blocks = 8 XCDs x 64; 8 whole heads per XCD.
    int fid = blockIdx.x;
    int xcd = fid & 7, idx = fid >> 3;       // idx 0..63
    int by = xcd * 8 + (idx >> 3);           // head-batch 0..63
    int bx = idx & 7;                        // q-block 0..7
    int b = by >> 4, h = by & 15;
    int q0 = bx * 128;

    // ---- mask precompute: madd2[1024] + per-64-tile flags ----
    {
        madd2[tid] = maskp[b * SEQ + tid] ? 0.f : MASKNEG;
        madd2[512 + tid] = maskp[b * SEQ + 512 + tid] ? 0.f : MASKNEG;
#pragma unroll
        for (int i = 0; i < 2; ++i) {
            int t = w * 2 + i;
            unsigned long long bl = __ballot(maskp[b * SEQ + t * 64 + lane] != 0);
            if (lane == 0) tflag[t] = (bl == ~0ull);
        }
    }

    // Q B-fragments (col=q=lane&31, k-slot ks: d = ks*16 + hi*8 + j); q-sub = wl
    bf16x8 qf[4];
    {
        const bf16* qb = Qp + ((size_t)(b * SEQ + q0 + wl * 32 + l31)) * D_MODEL + h * 64 + hi * 8;
#pragma unroll
        for (int ks = 0; ks < 4; ++ks) qf[ks] = *(const bf16x8*)(qb + ks * 16);
    }

    f32x16 oacc0 = {}, oacc1 = {};
    float lsum = 0.f;

    // stage tile t (0..7) of this wave's half into buf: global tile kt = hh*8 + t
    auto stage = [&](int buf, int t) {
        int kv0 = (hh * 8 + t) * 64;
        bf16* Kd = Kbuf + (size_t)(buf * 2 + hh) * 4096;
        bf16* Vd = Vbuf + (size_t)(buf * 2 + hh) * 4096;
#pragma unroll
        for (int i = 0; i < 2; ++i) {
            int seg = wl * 2 + i;                 // 0..7
            int row = seg * 8 + (lane >> 3);      // 0..63
            int cs = ((lane & 7) ^ (row & 7)) * 8;   // pre-swizzled source chunk
            const bf16* srcK = Kp + ((size_t)(b * SEQ + kv0 + row)) * D_MODEL + h * 64 + cs;
            __builtin_amdgcn_global_load_lds(
                (const __attribute__((address_space(1))) void*)srcK,
                (__attribute__((address_space(3))) void*)(Kd + seg * 512), 16, 0, 0);
            const bf16* srcV = VT + ((size_t)(b * 1024 + h * 64 + row)) * SEQ + kv0 + cs;
            __builtin_amdgcn_global_load_lds(
                (const __attribute__((address_space(1))) void*)srcV,
                (__attribute__((address_space(3))) void*)(Vd + seg * 512), 16, 0, 0);
        }
    };

    stage(0, 0);
    __syncthreads();

    for (int t = 0; t < 8; ++t) {
        int cur = t & 1;
        if (t + 1 < 8) stage(cur ^ 1, t + 1);
        int kt = hh * 8 + t;
        const bf16* Kl = Kbuf + (size_t)(cur * 2 + hh) * 4096;
        const bf16* Vl = Vbuf + (size_t)(cur * 2 + hh) * 4096;

        // ---- QK^T (swapped): S^T[kv][q] ----
        f32x16 p0 = {}, p1 = {};
        __builtin_amdgcn_s_setprio(1);
#pragma unroll
        for (int ks = 0; ks < 4; ++ks) {
            int sl = ((2 * ks + hi) ^ (l31 & 7)) * 8;
            bf16x8 k0 = *(const bf16x8*)(&Kl[l31 * 64 + sl]);
            bf16x8 k1 = *(const bf16x8*)(&Kl[(32 + l31) * 64 + sl]);
            p0 = __builtin_amdgcn_mfma_f32_32x32x16_bf16(k0, qf[ks], p0, 0, 0, 0);
            p1 = __builtin_amdgcn_mfma_f32_32x32x16_bf16(k1, qf[ks], p1, 0, 0, 0);
        }
        __builtin_amdgcn_s_setprio(0);

        // ---- exp2 + row-sum (reg r -> kv = (r&3) + 8*(r>>2) + 4*hi) ----
        float a0 = 0.f, a1 = 0.f, a2 = 0.f, a3 = 0.f;
        const float* mb = &madd2[kt * 64];
        if (tflag[kt]) {
#pragma unroll
            for (int g = 0; g < 4; ++g) {
                float s0 = 0.f, s1 = 0.f;
#pragma unroll
                for (int c = 0; c < 4; ++c) {
                    int r = g * 4 + c;
                    float e0 = EXP2(p0[r]);
                    float e1 = EXP2(p1[r]);
                    p0[r] = e0; p1[r] = e1;
                    s0 += e0; s1 += e1;
                }
                if (g == 0) a0 = s0 + s1;
                else if (g == 1) a1 = s0 + s1;
                else if (g == 2) a2 = s0 + s1;
                else a3 = s0 + s1;
            }
        } else {
#pragma unroll
            for (int g = 0; g < 4; ++g) {
                f32x4 mk0 = *(const f32x4*)(mb + g * 8 + hi * 4);
                f32x4 mk1 = *(const f32x4*)(mb + 32 + g * 8 + hi * 4);
                float s0 = 0.f, s1 = 0.f;
#pragma unroll
                for (int c = 0; c < 4; ++c) {
                    int r = g * 4 + c;
                    float e0 = EXP2(p0[r] + mk0[c]);
                    float e1 = EXP2(p1[r] + mk1[c]);
                    p0[r] = e0; p1[r] = e1;
                    s0 += e0; s1 += e1;
                }
                if (g == 0) a0 = s0 + s1;
                else if (g == 1) a1 = s0 + s1;
                else if (g == 2) a2 = s0 + s1;
                else a3 = s0 + s1;
            }
        }
        float acc_s = (a0 + a1) + (a2 + a3);
        acc_s += __shfl_xor(acc_s, 32);
        lsum += acc_s;

        // ---- pack P -> PV A-fragments (cvt_pk + permlane32_swap) ----
        union FragU { bf16x8 v; unsigned u[4]; };
        FragU pa0, pa1, pa2, pa3;
#define PKSW(PV, RA, RB, DST)  { \
            unsigned a_ = pkbf(PV[RA], PV[(RA) + 1]); \
            unsigned b_ = pkbf(PV[RB], PV[(RB) + 1]); \
            auto rr_ = __builtin_amdgcn_permlane32_swap(a_, b_, false, false); \
            DST.u[((RA) & 3) >> 1] = rr_[0]; DST.u[(((RA) & 3) >> 1) + 2] = rr_[1]; }
        PKSW(p0, 0, 4,  pa0);
        PKSW(p0, 2, 6,  pa0);
        PKSW(p0, 8, 12, pa1);
        PKSW(p0, 10, 14, pa1);
        PKSW(p1, 0, 4,  pa2);
        PKSW(p1, 2, 6,  pa2);
        PKSW(p1, 8, 12, pa3);
        PKSW(p1, 10, 14, pa3);
#undef PKSW

        // ---- PV: O += P[q][kv] . V[kv][d] ----
        __builtin_amdgcn_s_setprio(1);
#pragma unroll
        for (int ks = 0; ks < 4; ++ks) {
            bf16x8 pav = (ks == 0) ? pa0.v : (ks == 1) ? pa1.v : (ks == 2) ? pa2.v : pa3.v;
            int sl = ((2 * ks + hi) ^ (l31 & 7)) * 8;
            bf16x8 v0 = *(const bf16x8*)(&Vl[l31 * 64 + sl]);
            bf16x8 v1 = *(const bf16x8*)(&Vl[(32 + l31) * 64 + sl]);
            oacc0 = __builtin_amdgcn_mfma_f32_32x32x16_bf16(pav, v0, oacc0, 0, 0, 0);
            oacc1 = __builtin_amdgcn_mfma_f32_32x32x16_bf16(pav, v1, oacc1, 0, 0, 0);
        }
        __builtin_amdgcn_s_setprio(0);

        __syncthreads();
    }

    // ---- merge halves (exp2-space, no max => pure addition), then normalize+store ----
    float* Omrg = (float*)smem;              // [4][32][64]
    float* Lmrg = (float*)(smem + 32768);    // [4][32]
    if (hh == 1) {
#pragma unroll
        for (int g = 0; g < 4; ++g) {
#pragma unroll
            for (int c = 0; c < 4; ++c) {
                int r = g * 4 + c;
                int q = c + g * 8 + hi * 4;      // q-row within sub-tile
                Omrg[wl * 2048 + q * 64 + l31]      = oacc0[r];
                Omrg[wl * 2048 + q * 64 + 32 + l31] = oacc1[r];
            }
        }
        if (hi == 0) Lmrg[wl * 32 + l31] = lsum;
    }
    __syncthreads();
    if (hh == 0) {
        float ltot = lsum + Lmrg[wl * 32 + l31];   // lane l31 holds q=l31's denom
#pragma unroll
        for (int g = 0; g < 4; ++g) {
#pragma unroll
            for (int c = 0; c < 4; ++c) {
                int r = g * 4 + c;
                int q = c + g * 8 + hi * 4;
                float o0 = oacc0[r] + Omrg[wl * 2048 + q * 64 + l31];
                float o1 = oacc1[r] + Omrg[wl * 2048 + q * 64 + 32 + l31];
                float sden = __shfl(ltot, q);
                float inv = 1.0f / sden;
                int qg = q0 + wl * 32 + q;
                size_t base = ((size_t)(b * SEQ + qg)) * D_MODEL + h * 64;
                ctx[base + l31]      = (bf16)(o0 * inv);
                ctx[base + 32 + l31] = (bf16)(o1 * inv);
            }
        }
    }
}

// ---------------- launch ----------------
extern "C" void kernel_launch(void* const* d_in, const int* in_sizes, int n_in,
                              void* d_out, int out_size, void* d_ws, size_t ws_size,
                              hipStream_t stream) {
    const float* q  = (const float*)d_in[0];
    const float* k  = (const float*)d_in[1];
    const float* v  = (const float*)d_in[2];
    const int* mask = (const int*)d_in[3];
    const float* Wq = (const float*)d_in[4];
    const float* bq = (const float*)d_in[5];
    const float* Wk = (const float*)d_in[6];
    const float* bk = (const float*)d_in[7];
    const float* Wv = (const float*)d_in[8];
    const float* bv = (const float*)d_in[9];
    const float* Wo = (const float*)d_in[10];
    const float* bo = (const float*)d_in[11];
    float* out = (float*)d_out;

    char* ws = (char*)d_ws;
    size_t szQKV = (size_t)MTOT * D_MODEL * sizeof(bf16);   // 8 MB
    size_t szW = (size_t)D_MODEL * D_MODEL * sizeof(bf16);  // 2 MB
    bf16* qb  = (bf16*)ws; ws += szQKV;
    bf16* kb  = (bf16*)ws; ws += szQKV;
    bf16* vb  = (bf16*)ws; ws += szQKV;
    bf16* Wqb = (bf16*)ws; ws += szW;
    bf16* Wkb = (bf16*)ws; ws += szW;
    bf16* Wvb = (bf16*)ws; ws += szW;
    bf16* Wob = (bf16*)ws; ws += szW;
    bf16* Qp  = (bf16*)ws; ws += szQKV;
    bf16* Kp  = (bf16*)ws; ws += szQKV;
    bf16* VT  = (bf16*)ws; ws += szQKV;   // transposed V: [B][H][64][SEQ]
    bf16* ctx = (bf16*)ws; ws += szQKV;

    dim3 gc(512, 7, 1);
    cast_all<<<gc, 256, 0, stream>>>(q, k, v, Wq, Wk, Wv, Wo,
                                     qb, kb, vb, Wqb, Wkb, Wvb, Wob);

    dim3 g1(MTOT / 128, D_MODEL / 128, 3);
    gemm_bt<bf16, 0><<<g1, 256, 0, stream>>>(qb, kb, vb, Wqb, Wkb, Wvb,
                                             bq, bk, bv, Qp, Kp, VT);

    attn_fwd<<<dim3(512), 512, 0, stream>>>(Qp, Kp, VT, mask, ctx);

    dim3 g3(MTOT / 128, D_MODEL / 128, 1);
    gemm_bt<float, 1><<<g3, 256, 0, stream>>>(ctx, ctx, ctx, Wob, Wob, Wob,
                                              bo, bo, bo, out, out, out);
}

// Round 9
// 103.492 us; speedup vs baseline: 1.3360x; 1.0811x over previous
//
#include <hip/hip_runtime.h>
#include <hip/hip_bf16.h>
#include <math.h>

typedef __bf16 bf16;
typedef __bf16 bf16x8 __attribute__((ext_vector_type(8)));
typedef __bf16 bf16x2 __attribute__((ext_vector_type(2)));
typedef float f32x4 __attribute__((ext_vector_type(4)));
typedef float f32x16 __attribute__((ext_vector_type(16)));

#define D_MODEL 1024
#define SEQ 1024
#define BATCH 4
#define NHEAD 16
#define MTOT (BATCH*SEQ)   // 4096

// scores computed in exp2-space: fold 1/sqrt(64) * log2(e) into Q projection
#define QSCALE 0.18033688011112042f
#define MASKNEG -1e9f
#define EXP2(x) __builtin_amdgcn_exp2f(x)

// ---------------- fused f32 -> bf16 casts (7 tensors, one launch) ----------------
__global__ void cast_all(const float* __restrict__ s0, const float* __restrict__ s1,
                         const float* __restrict__ s2, const float* __restrict__ s3,
                         const float* __restrict__ s4, const float* __restrict__ s5,
                         const float* __restrict__ s6,
                         bf16* d0, bf16* d1, bf16* d2, bf16* d3, bf16* d4, bf16* d5, bf16* d6) {
    int z = blockIdx.y;
    const float* s; bf16* d; int n;
    switch (z) {
        case 0: s = s0; d = d0; n = MTOT * D_MODEL; break;
        case 1: s = s1; d = d1; n = MTOT * D_MODEL; break;
        case 2: s = s2; d = d2; n = MTOT * D_MODEL; break;
        case 3: s = s3; d = d3; n = D_MODEL * D_MODEL; break;
        case 4: s = s4; d = d4; n = D_MODEL * D_MODEL; break;
        case 5: s = s5; d = d5; n = D_MODEL * D_MODEL; break;
        default: s = s6; d = d6; n = D_MODEL * D_MODEL; break;
    }
    int idx = (blockIdx.x * blockDim.x + threadIdx.x) * 8;
    int stride = gridDim.x * blockDim.x * 8;
    for (int i = idx; i < n; i += stride) {
        const float4* p = (const float4*)(s + i);
        float4 a = p[0], b = p[1];
        bf16x8 o;
        o[0] = (bf16)a.x; o[1] = (bf16)a.y; o[2] = (bf16)a.z; o[3] = (bf16)a.w;
        o[4] = (bf16)b.x; o[5] = (bf16)b.y; o[6] = (bf16)b.z; o[7] = (bf16)b.w;
        *(bf16x8*)(d + i) = o;
    }
}

// ---------------- GEMM: C[M,N] = A[M,K] @ W[N,K]^T + bias ----------------
// Double-buffered LDS, ONE barrier per K-step: stage(next) -> MFMA(cur) -> barrier.
template<typename OT, int MODE>
__global__ __launch_bounds__(256, 3)
void gemm_bt(const bf16* __restrict__ A0, const bf16* __restrict__ A1, const bf16* __restrict__ A2,
             const bf16* __restrict__ W0, const bf16* __restrict__ W1, const bf16* __restrict__ W2,
             const float* __restrict__ bias0, const float* __restrict__ bias1, const float* __restrict__ bias2,
             OT* __restrict__ O0, OT* __restrict__ O1, OT* __restrict__ O2) {
    constexpr int BK = 32;
    constexpr int K = D_MODEL;
    constexpr int NT = K / BK;   // 32
    __shared__ alignas(16) bf16 As[2][128 * BK];
    __shared__ alignas(16) bf16 Bs[2][128 * BK];

    int z = (MODE == 0) ? blockIdx.z : 0;
    const bf16* A = (z == 0) ? A0 : (z == 1) ? A1 : A2;
    const bf16* W = (z == 0) ? W0 : (z == 1) ? W1 : W2;
    const float* bias = (z == 0) ? bias0 : (z == 1) ? bias1 : bias2;
    OT* Out = (z == 0) ? O0 : (z == 1) ? O1 : O2;

    int tid = threadIdx.x;
    int lane = tid & 63, w = tid >> 6;
    int l15 = lane & 15, l4 = lane >> 4;
    int m0 = blockIdx.x * 128;
    int n0 = blockIdx.y * 128;
    int wm = w >> 1, wn = w & 1;

    f32x4 acc[4][4] = {};

    int srow = lane >> 2;
    int scol = (lane & 3) * 8;

    auto stage = [&](int buf, int kt) {
#pragma unroll
        for (int i = 0; i < 2; ++i) {
            int seg = w * 2 + i;
            int row = seg * 16 + srow;
            const bf16* srcA = A + (size_t)(m0 + row) * K + kt * BK + scol;
            const bf16* srcB = W + (size_t)(n0 + row) * K + kt * BK + scol;
            __builtin_amdgcn_global_load_lds(
                (const __attribute__((address_space(1))) void*)srcA,
                (__attribute__((address_space(3))) void*)(&As[buf][seg * 512]), 16, 0, 0);
            __builtin_amdgcn_global_load_lds(
                (const __attribute__((address_space(1))) void*)srcB,
                (__attribute__((address_space(3))) void*)(&Bs[buf][seg * 512]), 16, 0, 0);
        }
    };

    stage(0, 0);
    __syncthreads();

    for (int kt = 0; kt < NT; ++kt) {
        int cur = kt & 1;
        if (kt + 1 < NT) stage(cur ^ 1, kt + 1);

        const bf16* pa = &As[cur][(wm * 64 + l15) * BK + l4 * 8];
        const bf16* pb = &Bs[cur][(wn * 64 + l15) * BK + l4 * 8];
        bf16x8 af[4], bv[4];
#pragma unroll
        for (int m = 0; m < 4; ++m) af[m] = *(const bf16x8*)(pa + m * 16 * BK);
#pragma unroll
        for (int n = 0; n < 4; ++n) bv[n] = *(const bf16x8*)(pb + n * 16 * BK);
#pragma unroll
        for (int m = 0; m < 4; ++m)
#pragma unroll
            for (int n = 0; n < 4; ++n)
                acc[m][n] = __builtin_amdgcn_mfma_f32_16x16x32_bf16(af[m], bv[n], acc[m][n], 0, 0, 0);

        __syncthreads();
    }

    float bload[4];
#pragma unroll
    for (int n = 0; n < 4; ++n) bload[n] = bias[n0 + wn * 64 + n * 16 + l15];

    if (MODE == 0 && z == 2) {
        // V stored transposed: VT[(b*1024 + h*64+d)][s]
#pragma unroll
        for (int m = 0; m < 4; ++m) {
            int row = m0 + wm * 64 + m * 16 + l4 * 4;
#pragma unroll
            for (int n = 0; n < 4; ++n) {
                int col = n0 + wn * 64 + n * 16 + l15;
                float bl = bload[n];
#pragma unroll
                for (int r = 0; r < 4; ++r) {
                    float vv = acc[m][n][r] + bl;
                    int rr = row + r;
                    int bb = rr >> 10, s = rr & 1023;
                    Out[((size_t)(bb * 1024 + col)) * 1024 + s] = (OT)vv;
                }
            }
        }
    } else {
        const float sc = (MODE == 0 && z == 0) ? QSCALE : 1.0f;
#pragma unroll
        for (int m = 0; m < 4; ++m) {
            int row = m0 + wm * 64 + m * 16 + l4 * 4;
#pragma unroll
            for (int n = 0; n < 4; ++n) {
                int col = n0 + wn * 64 + n * 16 + l15;
                float bl = bload[n];
#pragma unroll
                for (int r = 0; r < 4; ++r) {
                    float vv = (acc[m][n][r] + bl) * sc;
                    Out[(size_t)(row + r) * D_MODEL + col] = (OT)vv;
                }
            }
        }
    }
}

// ---------------- Flash attention fwd: intra-block split-KV, 8 waves, LOW-VGPR ----------------
// Waves 0-3: kv [0,512); waves 4-7: kv [512,1024); same 128 q-rows. Exp2-space no-max
// softmax => halves merge by PURE ADDITION in LDS epilogue. 16 waves/CU.
// REGISTER FIX vs R8: each 64-kv tile processed as TWO 32-kv chains (QK^T -> exp2 ->
// pack -> PV immediately), so only ONE f32x16 score block is live at a time:
// peak ~= oacc(32,AGPR) + qf(16) + p(16) + pack(8) + transients < 128 unified -> no spill.
__device__ __forceinline__ unsigned pkbf(float lo, float hi2) {
    bf16x2 t; t[0] = (bf16)lo; t[1] = (bf16)hi2;
    return __builtin_bit_cast(unsigned, t);
}

__global__ __launch_bounds__(512, 4)
void attn_fwd(const bf16* __restrict__ Qp, const bf16* __restrict__ Kp,
              const bf16* __restrict__ VT, const int* __restrict__ maskp,
              bf16* __restrict__ ctx) {
    // smem: [0,32K) Kbuf [2buf][2half][4096]; [32K,64K) Vbuf; [64K,68K) madd2; [68K,+64) tflag.
    // Epilogue reuse: [0,32K) Omrg[4][32][64] f32; [32K,+512) Lmrg[4][32] f32.
    __shared__ alignas(16) unsigned char smem[69760];
    bf16* Kbuf = (bf16*)smem;
    bf16* Vbuf = (bf16*)(smem + 32768);
    float* madd2 = (float*)(smem + 65536);
    int* tflag = (int*)(smem + 69632);

    int tid = threadIdx.x;
    int lane = tid & 63, w = tid >> 6;      // 8 waves
    int l31 = lane & 31, hi = lane >> 5;
    int hh = w >> 2, wl = w & 3;            // kv-half, wave-in-half (= q-sub)

    // XCD swizzle: 512 blocks = 8 XCDs x 64; 8 whole heads per XCD.
    int fid = blockIdx.x;
    int xcd = fid & 7, idx = fid >> 3;       // idx 0..63
    int by = xcd * 8 + (idx >> 3);           // head-batch 0..63
    int bx = idx & 7;                        // q-block 0..7
    int b = by >> 4, h = by & 15;
    int q0 = bx * 128;

    // ---- mask precompute: madd2[1024] + per-64-tile flags ----
    {
        madd2[tid] = maskp[b * SEQ + tid] ? 0.f : MASKNEG;
        madd2[512 + tid] = maskp[b * SEQ + 512 + tid] ? 0.f : MASKNEG;
#pragma unroll
        for (int i = 0; i < 2; ++i) {
            int t = w * 2 + i;
            unsigned long long bl = __ballot(maskp[b * SEQ + t * 64 + lane] != 0);
            if (lane == 0) tflag[t] = (bl == ~0ull);
        }
    }

    // Q B-fragments (col=q=lane&31, k-slot ks: d = ks*16 + hi*8 + j); q-sub = wl
    bf16x8 qf[4];
    {
        const bf16* qb = Qp + ((size_t)(b * SEQ + q0 + wl * 32 + l31)) * D_MODEL + h * 64 + hi * 8;
#pragma unroll
        for (int ks = 0; ks < 4; ++ks) qf[ks] = *(const bf16x8*)(qb + ks * 16);
    }

    f32x16 oacc0 = {}, oacc1 = {};
    float lsum = 0.f;

    // stage tile t (0..7) of this wave's half into buf: global tile kt = hh*8 + t
    auto stage = [&](int buf, int t) {
        int kv0 = (hh * 8 + t) * 64;
        bf16* Kd = Kbuf + (size_t)(buf * 2 + hh) * 4096;
        bf16* Vd = Vbuf + (size_t)(buf * 2 + hh) * 4096;
#pragma unroll
        for (int i = 0; i < 2; ++i) {
            int seg = wl * 2 + i;                 // 0..7
            int row = seg * 8 + (lane >> 3);      // 0..63
            int cs = ((lane & 7) ^ (row & 7)) * 8;   // pre-swizzled source chunk
            const bf16* srcK = Kp + ((size_t)(b * SEQ + kv0 + row)) * D_MODEL + h * 64 + cs;
            __builtin_amdgcn_global_load_lds(
                (const __attribute__((address_space(1))) void*)srcK,
                (__attribute__((address_space(3))) void*)(Kd + seg * 512), 16, 0, 0);
            const bf16* srcV = VT + ((size_t)(b * 1024 + h * 64 + row)) * SEQ + kv0 + cs;
            __builtin_amdgcn_global_load_lds(
                (const __attribute__((address_space(1))) void*)srcV,
                (__attribute__((address_space(3))) void*)(Vd + seg * 512), 16, 0, 0);
        }
    };

    // process one 32-kv score chain: exp2+sum, pack, PV (ks = ksb, ksb+1)
    auto half_p = [&](f32x16& p, const float* mbh, int flag, const bf16* Vl, int ksb) -> float {
        float a0 = 0.f, a1 = 0.f, a2 = 0.f, a3 = 0.f;
        if (flag) {
#pragma unroll
            for (int g = 0; g < 4; ++g) {
                float s0 = 0.f;
#pragma unroll
                for (int c = 0; c < 4; ++c) {
                    int r = g * 4 + c;
                    float e = EXP2(p[r]);
                    p[r] = e; s0 += e;
                }
                if (g == 0) a0 = s0; else if (g == 1) a1 = s0;
                else if (g == 2) a2 = s0; else a3 = s0;
            }
        } else {
#pragma unroll
            for (int g = 0; g < 4; ++g) {
                f32x4 mk = *(const f32x4*)(mbh + g * 8 + hi * 4);
                float s0 = 0.f;
#pragma unroll
                for (int c = 0; c < 4; ++c) {
                    int r = g * 4 + c;
                    float e = EXP2(p[r] + mk[c]);
                    p[r] = e; s0 += e;
                }
                if (g == 0) a0 = s0; else if (g == 1) a1 = s0;
                else if (g == 2) a2 = s0; else a3 = s0;
            }
        }
        // pack (cvt_pk + permlane32_swap): regs 0-7 -> A0 (k-slot ksb), 8-15 -> A1 (ksb+1)
        union FragU { bf16x8 v; unsigned u[4]; };
        FragU A0, A1;
#define PKSW(PV, RA, RB, DST)  { \
            unsigned a_ = pkbf(PV[RA], PV[(RA) + 1]); \
            unsigned b_ = pkbf(PV[RB], PV[(RB) + 1]); \
            auto rr_ = __builtin_amdgcn_permlane32_swap(a_, b_, false, false); \
            DST.u[((RA) & 3) >> 1] = rr_[0]; DST.u[(((RA) & 3) >> 1) + 2] = rr_[1]; }
        PKSW(p, 0, 4,  A0);
        PKSW(p, 2, 6,  A0);
        PKSW(p, 8, 12, A1);
        PKSW(p, 10, 14, A1);
#undef PKSW
        __builtin_amdgcn_s_setprio(1);
#pragma unroll
        for (int i = 0; i < 2; ++i) {
            int ks = ksb + i;
            bf16x8 pav = i ? A1.v : A0.v;
            int sl = ((2 * ks + hi) ^ (l31 & 7)) * 8;
            bf16x8 v0 = *(const bf16x8*)(&Vl[l31 * 64 + sl]);
            bf16x8 v1 = *(const bf16x8*)(&Vl[(32 + l31) * 64 + sl]);
            oacc0 = __builtin_amdgcn_mfma_f32_32x32x16_bf16(pav, v0, oacc0, 0, 0, 0);
            oacc1 = __builtin_amdgcn_mfma_f32_32x32x16_bf16(pav, v1, oacc1, 0, 0, 0);
        }
        __builtin_amdgcn_s_setprio(0);
        return (a0 + a1) + (a2 + a3);
    };

    stage(0, 0);
    __syncthreads();

    for (int t = 0; t < 8; ++t) {
        int cur = t & 1;
        if (t + 1 < 8) stage(cur ^ 1, t + 1);
        int kt = hh * 8 + t;
        const bf16* Kl = Kbuf + (size_t)(cur * 2 + hh) * 4096;
        const bf16* Vl = Vbuf + (size_t)(cur * 2 + hh) * 4096;
        const float* mb = &madd2[kt * 64];
        int flag = tflag[kt];

        float ts;
        {   // chain A: kv rows [0,32) of tile
            f32x16 p = {};
            __builtin_amdgcn_s_setprio(1);
#pragma unroll
            for (int ks = 0; ks < 4; ++ks) {
                int sl = ((2 * ks + hi) ^ (l31 & 7)) * 8;
                bf16x8 k0 = *(const bf16x8*)(&Kl[l31 * 64 + sl]);
                p = __builtin_amdgcn_mfma_f32_32x32x16_bf16(k0, qf[ks], p, 0, 0, 0);
            }
            __builtin_amdgcn_s_setprio(0);
            ts = half_p(p, mb, flag, Vl, 0);
        }
        {   // chain B: kv rows [32,64) of tile
            f32x16 p = {};
            __builtin_amdgcn_s_setprio(1);
#pragma unroll
            for (int ks = 0; ks < 4; ++ks) {
                int sl = ((2 * ks + hi) ^ (l31 & 7)) * 8;
                bf16x8 k1 = *(const bf16x8*)(&Kl[(32 + l31) * 64 + sl]);
                p = __builtin_amdgcn_mfma_f32_32x32x16_bf16(k1, qf[ks], p, 0, 0, 0);
            }
            __builtin_amdgcn_s_setprio(0);
            ts += half_p(p, mb + 32, flag, Vl, 2);
        }
        ts += __shfl_xor(ts, 32);
        lsum += ts;

        __syncthreads();
    }

    // ---- merge halves (exp2-space, no max => pure addition), then normalize+store ----
    float* Omrg = (float*)smem;              // [4][32][64]
    float* Lmrg = (float*)(smem + 32768);    // [4][32]
    if (hh == 1) {
#pragma unroll
        for (int g = 0; g < 4; ++g) {
#pragma unroll
            for (int c = 0; c < 4; ++c) {
                int r = g * 4 + c;
                int q = c + g * 8 + hi * 4;      // q-row within sub-tile
                Omrg[wl * 2048 + q * 64 + l31]      = oacc0[r];
                Omrg[wl * 2048 + q * 64 + 32 + l31] = oacc1[r];
            }
        }
        if (hi == 0) Lmrg[wl * 32 + l31] = lsum;
    }
    __syncthreads();
    if (hh == 0) {
        float ltot = lsum + Lmrg[wl * 32 + l31];   // lane l31 holds q=l31's denom
#pragma unroll
        for (int g = 0; g < 4; ++g) {
#pragma unroll
            for (int c = 0; c < 4; ++c) {
                int r = g * 4 + c;
                int q = c + g * 8 + hi * 4;
                float o0 = oacc0[r] + Omrg[wl * 2048 + q * 64 + l31];
                float o1 = oacc1[r] + Omrg[wl * 2048 + q * 64 + 32 + l31];
                float sden = __shfl(ltot, q);
                float inv = 1.0f / sden;
                int qg = q0 + wl * 32 + q;
                size_t base = ((size_t)(b * SEQ + qg)) * D_MODEL + h * 64;
                ctx[base + l31]      = (bf16)(o0 * inv);
                ctx[base + 32 + l31] = (bf16)(o1 * inv);
            }
        }
    }
}

// ---------------- launch ----------------
extern "C" void kernel_launch(void* const* d_in, const int* in_sizes, int n_in,
                              void* d_out, int out_size, void* d_ws, size_t ws_size,
                              hipStream_t stream) {
    const float* q  = (const float*)d_in[0];
    const float* k  = (const float*)d_in[1];
    const float* v  = (const float*)d_in[2];
    const int* mask = (const int*)d_in[3];
    const float* Wq = (const float*)d_in[4];
    const float* bq = (const float*)d_in[5];
    const float* Wk = (const float*)d_in[6];
    const float* bk = (const float*)d_in[7];
    const float* Wv = (const float*)d_in[8];
    const float* bv = (const float*)d_in[9];
    const float* Wo = (const float*)d_in[10];
    const float* bo = (const float*)d_in[11];
    float* out = (float*)d_out;

    char* ws = (char*)d_ws;
    size_t szQKV = (size_t)MTOT * D_MODEL * sizeof(bf16);   // 8 MB
    size_t szW = (size_t)D_MODEL * D_MODEL * sizeof(bf16);  // 2 MB
    bf16* qb  = (bf16*)ws; ws += szQKV;
    bf16* kb  = (bf16*)ws; ws += szQKV;
    bf16* vb  = (bf16*)ws; ws += szQKV;
    bf16* Wqb = (bf16*)ws; ws += szW;
    bf16* Wkb = (bf16*)ws; ws += szW;
    bf16* Wvb = (bf16*)ws; ws += szW;
    bf16* Wob = (bf16*)ws; ws += szW;
    bf16* Qp  = (bf16*)ws; ws += szQKV;
    bf16* Kp  = (bf16*)ws; ws += szQKV;
    bf16* VT  = (bf16*)ws; ws += szQKV;   // transposed V: [B][H][64][SEQ]
    bf16* ctx = (bf16*)ws; ws += szQKV;

    dim3 gc(512, 7, 1);
    cast_all<<<gc, 256, 0, stream>>>(q, k, v, Wq, Wk, Wv, Wo,
                                     qb, kb, vb, Wqb, Wkb, Wvb, Wob);

    dim3 g1(MTOT / 128, D_MODEL / 128, 3);
    gemm_bt<bf16, 0><<<g1, 256, 0, stream>>>(qb, kb, vb, Wqb, Wkb, Wvb,
                                             bq, bk, bv, Qp, Kp, VT);

    attn_fwd<<<dim3(512), 512, 0, stream>>>(Qp, Kp, VT, mask, ctx);

    dim3 g3(MTOT / 128, D_MODEL / 128, 1);
    gemm_bt<float, 1><<<g3, 256, 0, stream>>>(ctx, ctx, ctx, Wob, Wob, Wob,
                                              bo, bo, bo, out, out, out);
}